// Round 1
// 2098.900 us; speedup vs baseline: 1.1543x; 1.1543x over previous
//
#include <hip/hip_runtime.h>
#include <hip/hip_bf16.h>

// Problem constants
#define BB   4096
#define CC   16
#define HIDN 1024
#define NHD  16
#define HDIM 64
#define MROWS (BB*CC)   // 65536
#define QKVN 3072

using u16 = unsigned short;
typedef __bf16 bf16x8 __attribute__((ext_vector_type(8)));
typedef float  f32x4  __attribute__((ext_vector_type(4)));

__device__ __forceinline__ u16 f2b(float f) {
  union { __hip_bfloat16 h; u16 u; } c;
  c.h = __float2bfloat16(f);
  return c.u;
}

// ---------------------------------------------------------------------------
// Weight transpose + cast fp32 (R x C) -> bf16 (C x R)
// ---------------------------------------------------------------------------
__global__ __launch_bounds__(256) void transpose_cast(
    const float* __restrict__ src, u16* __restrict__ dst, int R, int C) {
  __shared__ float tile[32][33];
  const int bx = blockIdx.x * 32;  // col base in src
  const int by = blockIdx.y * 32;  // row base in src
  const int tx = threadIdx.x, ty = threadIdx.y;
#pragma unroll
  for (int jj = 0; jj < 32; jj += 8)
    tile[ty + jj][tx] = src[(long long)(by + ty + jj) * C + bx + tx];
  __syncthreads();
#pragma unroll
  for (int jj = 0; jj < 32; jj += 8)
    dst[(long long)(bx + ty + jj) * R + by + tx] = f2b(tile[tx][ty + jj]);
}

// ---------------------------------------------------------------------------
// Row LayerNorm fp32 -> bf16.  One block (256 thr) per row of 1024.
// ---------------------------------------------------------------------------
__global__ __launch_bounds__(256) void ln_kernel(
    const float* __restrict__ x, const float* __restrict__ g,
    const float* __restrict__ b, u16* __restrict__ out) {
  const int row = blockIdx.x;
  const int t = threadIdx.x;
  const float4 v = ((const float4*)(x + (long long)row * HIDN))[t];
  float s  = v.x + v.y + v.z + v.w;
  float sq = v.x * v.x + v.y * v.y + v.z * v.z + v.w * v.w;
#pragma unroll
  for (int off = 32; off; off >>= 1) {
    s  += __shfl_down(s, off);
    sq += __shfl_down(sq, off);
  }
  __shared__ float ws[8];
  const int w = t >> 6, lane = t & 63;
  if (lane == 0) { ws[w] = s; ws[4 + w] = sq; }
  __syncthreads();
  const float S  = ws[0] + ws[1] + ws[2] + ws[3];
  const float SQ = ws[4] + ws[5] + ws[6] + ws[7];
  const float mean = S * (1.f / HIDN);
  const float var  = SQ * (1.f / HIDN) - mean * mean;
  const float rstd = rsqrtf(var + 1e-5f);
  const float4 gg = ((const float4*)g)[t];
  const float4 bb = ((const float4*)b)[t];
  ushort4 o;
  o.x = f2b((v.x - mean) * rstd * gg.x + bb.x);
  o.y = f2b((v.y - mean) * rstd * gg.y + bb.y);
  o.z = f2b((v.z - mean) * rstd * gg.z + bb.z);
  o.w = f2b((v.w - mean) * rstd * gg.w + bb.w);
  ((ushort4*)(out + (long long)row * HIDN))[t] = o;
}

// ---------------------------------------------------------------------------
// GEMM: C[M,N] = A[M,K] @ B[K,N], A bf16 row-major, BT = B^T bf16 (N x K).
// 256x256 tile, BK=64, 512 threads = 8 waves (2M x 4N), 128 KiB LDS dbuf.
// 8-phase-style schedule: per K-tile 4 phases, each
//   { ds_read subtile ; issue half-tile global_load_lds prefetch ;
//     counted s_waitcnt vmcnt(N) ; s_barrier ; setprio+16 MFMA ; s_barrier }
// Prefetch targets the alternate buffer only; every overwritten LDS region's
// last reader is >=4 barriers upstream -> race-free by construction.
// LDS chunk swizzle kc ^ (row&7) (conflict-free, SQ_LDS_BANK_CONFLICT==0 at
// 128 tile) applied on the global source side (global_load_lds dest linear).
// EPI: 1 = fused QKV (per-block bias select + ct_key on K cols) -> bf16
//      2 = bias + fp32 residual -> fp32 ; 3 = bias + ELU -> bf16
// ---------------------------------------------------------------------------
#define TBM 256
#define TBN 256
#define TBK 64

template <int EPI>
__global__ __launch_bounds__(512, 2) void gemm256(
    const u16* __restrict__ A, const u16* __restrict__ BT, int K,
    const float* __restrict__ bias, const float* __restrict__ bias2,
    const float* __restrict__ bias3, const float* __restrict__ resid,
    const int* __restrict__ ctype, const float* __restrict__ ct_key,
    float* __restrict__ outF, u16* __restrict__ outB, int N) {
  // [buf][A=0/B=1][256 rows x 8 chunks x 8 u16]  = 128 KiB
  __shared__ __align__(16) u16 smem[2][2][TBM * TBK];

  const int t = threadIdx.x;
  const int lane = t & 63;
  const int w = t >> 6;
  const int l15 = lane & 15;
  const int quad = lane >> 4;
  const int wrow = w >> 2;  // 0..1 : 64-row group inside each 128-row half
  const int wcol = w & 3;   // 0..3 : 32-col group inside each 128-col half

  // bijective XCD swizzle (nwg % 8 == 0 for all launches here)
  const int gx = gridDim.x;
  const int nwg = gx * (int)gridDim.y;
  const int flat = (int)blockIdx.y * gx + (int)blockIdx.x;
  const int logical = (flat & 7) * (nwg >> 3) + (flat >> 3);
  const int nblk = logical % gx;  // N fast within an XCD chunk
  const int mblk = logical / gx;

  const long long Abase = (long long)mblk * TBM * K;
  const long long Bbase = (long long)nblk * TBN * K;

  // Stage one half-tile (128 rows x 64 k) of matrix `mat` into buf.
  // Linear LDS dest (wave base + lane*16); swizzle applied on global source.
  #define STAGE(buf, mat, h, kk, base, gp)                                       \
  do {                                                                           \
    _Pragma("unroll") for (int s_ = 0; s_ < 2; ++s_) {                           \
      const int idx_ = (h) * 1024 + (w * 2 + s_) * 64 + lane;                    \
      const int row_ = idx_ >> 3;                                                \
      const int kc_ = (idx_ & 7) ^ (row_ & 7);                                   \
      const u16* g_ = (gp) + (base) + (long long)row_ * K + (kk) + kc_ * 8;      \
      __builtin_amdgcn_global_load_lds(                                          \
          (const __attribute__((address_space(1))) void*)g_,                     \
          (__attribute__((address_space(3))) void*)(&smem[buf][mat][idx_ * 8]),  \
          16, 0, 0);                                                             \
    }                                                                            \
  } while (0)

  bf16x8 aR[4][2];   // 4 m-frags x 2 k-steps  (reused across the j phases)
  bf16x8 bR[2][2];   // 2 n-frags x 2 k-steps  (re-read per j)

  #define RDA(cb, i)                                                             \
  do {                                                                           \
    _Pragma("unroll") for (int fm_ = 0; fm_ < 4; ++fm_) {                        \
      const int row_ = (i) * 128 + wrow * 64 + fm_ * 16 + l15;                   \
      _Pragma("unroll") for (int ks_ = 0; ks_ < 2; ++ks_) {                      \
        const int kc_ = ks_ * 4 + quad;                                          \
        aR[fm_][ks_] = *(const bf16x8*)(                                         \
            &smem[cb][0][(row_ * 8 + (kc_ ^ (row_ & 7))) * 8]);                  \
      }                                                                          \
    }                                                                            \
  } while (0)

  #define RDB(cb, j)                                                             \
  do {                                                                           \
    _Pragma("unroll") for (int fn_ = 0; fn_ < 2; ++fn_) {                        \
      const int row_ = (j) * 128 + wcol * 32 + fn_ * 16 + l15;                   \
      _Pragma("unroll") for (int ks_ = 0; ks_ < 2; ++ks_) {                      \
        const int kc_ = ks_ * 4 + quad;                                          \
        bR[fn_][ks_] = *(const bf16x8*)(                                         \
            &smem[cb][1][(row_ * 8 + (kc_ ^ (row_ & 7))) * 8]);                  \
      }                                                                          \
    }                                                                            \
  } while (0)

  f32x4 acc[2][2][4][2] = {};  // [i row-half][j col-half][fm][fn]

  #define MM(i, j)                                                               \
  do {                                                                           \
    __builtin_amdgcn_s_setprio(1);                                               \
    _Pragma("unroll") for (int fm_ = 0; fm_ < 4; ++fm_)                          \
      _Pragma("unroll") for (int fn_ = 0; fn_ < 2; ++fn_)                        \
        _Pragma("unroll") for (int ks_ = 0; ks_ < 2; ++ks_)                      \
          acc[i][j][fm_][fn_] = __builtin_amdgcn_mfma_f32_16x16x32_bf16(         \
              aR[fm_][ks_], bR[fn_][ks_], acc[i][j][fm_][fn_], 0, 0, 0);         \
    __builtin_amdgcn_s_setprio(0);                                               \
  } while (0)

  #define WAITV(n) asm volatile("s_waitcnt vmcnt(" #n ")" ::: "memory")
  #define BAR() __builtin_amdgcn_s_barrier()

  // ---- prologue: tile 0, issue order [Ah0, Bh0, Bh1, Ah1] (8 loads)
  STAGE(0, 0, 0, 0, Abase, A);
  STAGE(0, 1, 0, 0, Bbase, BT);
  STAGE(0, 1, 1, 0, Bbase, BT);
  STAGE(0, 0, 1, 0, Abase, A);
  WAITV(4);          // Ah0(0), Bh0(0) resident; Bh1(0), Ah1(0) in flight
  BAR();

  const int NT = K >> 6;
  for (int tt = 0; tt < NT - 1; ++tt) {
    const int cb = tt & 1, nb = cb ^ 1;
    const int kk = (tt + 1) << 6;
    // ph1: C(0,0).  Issue Ah0,Bh0(t+1).  Need Bh1(t) by ph2.
    RDA(cb, 0); RDB(cb, 0);
    STAGE(nb, 0, 0, kk, Abase, A);
    STAGE(nb, 1, 0, kk, Bbase, BT);
    WAITV(6); BAR();
    MM(0, 0);
    BAR();
    // ph2: C(0,1).  Issue Bh1(t+1).  Need Ah1(t) by ph3.
    RDB(cb, 1);
    STAGE(nb, 1, 1, kk, Bbase, BT);
    WAITV(6); BAR();
    MM(0, 1);
    BAR();
    // ph3: C(1,1).  Issue Ah1(t+1).  Nothing new needed by ph4.
    RDA(cb, 1);
    STAGE(nb, 0, 1, kk, Abase, A);
    BAR();
    MM(1, 1);
    BAR();
    // ph4: C(1,0).  Need Ah0,Bh0(t+1) by next ph1.
    RDB(cb, 0);
    WAITV(4); BAR();
    MM(1, 0);
    BAR();
  }
  // ---- last tile (no prefetch): drain 2 -> 0
  {
    const int cb = (NT - 1) & 1;
    RDA(cb, 0); RDB(cb, 0);
    WAITV(2); BAR();
    MM(0, 0);
    BAR();
    RDB(cb, 1);
    WAITV(0); BAR();
    MM(0, 1);
    BAR();
    RDA(cb, 1);
    MM(1, 1);
    RDB(cb, 0);
    MM(1, 0);
  }

  #undef STAGE
  #undef RDA
  #undef RDB
  #undef MM
  #undef WAITV
  #undef BAR

  // ---- epilogue.  C/D layout: col = lane&15, row = quad*4 + r  (unchanged)
  const float* bsel = bias;
  bool addct = false;
  if constexpr (EPI == 1) {
    const int sub = nblk >> 2;  // 256-col block fully inside one 1024 slice
    bsel = (sub == 0) ? bias : (sub == 1 ? bias2 : bias3);
    addct = (sub == 1);
  }

#pragma unroll
  for (int i = 0; i < 2; ++i) {
#pragma unroll
    for (int j = 0; j < 2; ++j) {
#pragma unroll
      for (int fn = 0; fn < 2; ++fn) {
        const int col = nblk * TBN + j * 128 + wcol * 32 + fn * 16 + l15;
        float bv;
        if constexpr (EPI == 1) {
          bv = bsel[col & 1023];
        } else {
          bv = bias[col];
        }
#pragma unroll
        for (int fm = 0; fm < 4; ++fm) {
#pragma unroll
          for (int r = 0; r < 4; ++r) {
            const int row =
                mblk * TBM + i * 128 + wrow * 64 + fm * 16 + quad * 4 + r;
            float v = acc[i][j][fm][fn][r] + bv;
            const long long oidx = (long long)row * N + col;
            if constexpr (EPI == 1) {
              if (addct)
                v += ct_key[(long long)ctype[row >> 4] * HIDN + (col & 1023)];
              outB[oidx] = f2b(v);
            } else if constexpr (EPI == 2) {
              outF[oidx] = v + resid[oidx];
            } else if constexpr (EPI == 3) {
              v = v > 0.f ? v : __expf(v) - 1.f;
              outB[oidx] = f2b(v);
            } else {
              outB[oidx] = f2b(v);
            }
          }
        }
      }
    }
  }
}

// ---------------------------------------------------------------------------
// Per-batch attention. 1 block / batch, thread = (head h, query i).
// QKV bf16 interleaved (MROWS x 3072): [Q(1024) | K(1024) | V(1024)] per row.
// out bf16 (MROWS x 1024).
// ---------------------------------------------------------------------------
__global__ __launch_bounds__(256) void attn_kernel(
    const u16* __restrict__ QKV, const int* __restrict__ cancer_type,
    const int* __restrict__ channel_active,
    const float* __restrict__ ct_bias_emb, u16* __restrict__ out) {
  __shared__ u16 Ks[CC * HIDN];  // 32 KB
  __shared__ u16 Vs[CC * HIDN];  // 32 KB
  const int b = blockIdx.x;
  const int t = threadIdx.x;

#pragma unroll
  for (int j = 0; j < 8; ++j) {
    const int c = j * 256 + t;     // c = row*128 + off
    const int row = c >> 7;
    const int off = c & 127;
    const long long base = (long long)(b * CC + row) * QKVN;
    ((float4*)Ks)[c] = *(const float4*)(QKV + base + 1024 + off * 8);
    ((float4*)Vs)[c] = *(const float4*)(QKV + base + 2048 + off * 8);
  }
  __syncthreads();

  const int h = t >> 4, i = t & 15;
  const int ct = cancer_type[b];
  const float* ctb = ct_bias_emb + ct * (CC * CC) + i * CC;

  // load q row (64 floats)
  float q[HDIM];
  const u16* qg = QKV + ((long long)(b * CC + i) * QKVN + h * HDIM);
#pragma unroll
  for (int c = 0; c < 8; ++c) {
    const bf16x8 v = *(const bf16x8*)(qg + c * 8);
#pragma unroll
    for (int e = 0; e < 8; ++e) q[c * 8 + e] = (float)v[e];
  }

  // scores
  float s[CC];
#pragma unroll
  for (int j = 0; j < CC; ++j) {
    const u16* kr = Ks + j * HIDN + h * HDIM;
    float a = 0.f;
#pragma unroll
    for (int c = 0; c < 8; ++c) {
      const bf16x8 kv = *(const bf16x8*)(kr + c * 8);
#pragma unroll
      for (int e = 0; e < 8; ++e) a += q[c * 8 + e] * (float)kv[e];
    }
    a = a * 0.125f + 0.1f * ctb[j];
    if (channel_active[b * CC + j] == 0) a = -__builtin_inff();
    s[j] = a;
  }

  // softmax with all-masked -> zeros (nan_to_num)
  float mx = -__builtin_inff();
#pragma unroll
  for (int j = 0; j < CC; ++j) mx = fmaxf(mx, s[j]);
  float p[CC];
  float sum = 0.f;
  const bool dead = (mx == -__builtin_inff());
#pragma unroll
  for (int j = 0; j < CC; ++j) {
    p[j] = dead ? 0.f : __expf(s[j] - mx);
    sum += p[j];
  }
  const float inv = sum > 0.f ? 1.f / sum : 0.f;

  // P @ V
  float o[HDIM] = {};
#pragma unroll
  for (int j = 0; j < CC; ++j) {
    const float pw = p[j] * inv;
    const u16* vr = Vs + j * HIDN + h * HDIM;
#pragma unroll
    for (int c = 0; c < 8; ++c) {
      const bf16x8 vv = *(const bf16x8*)(vr + c * 8);
#pragma unroll
      for (int e = 0; e < 8; ++e) o[c * 8 + e] += pw * (float)vv[e];
    }
  }

  u16* og = out + ((long long)(b * CC + i) * HIDN + h * HDIM);
#pragma unroll
  for (int c = 0; c < 8; ++c) {
    uint4 u;
    u.x = (unsigned)f2b(o[c * 8 + 0]) | ((unsigned)f2b(o[c * 8 + 1]) << 16);
    u.y = (unsigned)f2b(o[c * 8 + 2]) | ((unsigned)f2b(o[c * 8 + 3]) << 16);
    u.z = (unsigned)f2b(o[c * 8 + 4]) | ((unsigned)f2b(o[c * 8 + 5]) << 16);
    u.w = (unsigned)f2b(o[c * 8 + 6]) | ((unsigned)f2b(o[c * 8 + 7]) << 16);
    ((uint4*)og)[c] = u;
  }
}

// ---------------------------------------------------------------------------
extern "C" void kernel_launch(void* const* d_in, const int* in_sizes, int n_in,
                              void* d_out, int out_size, void* d_ws,
                              size_t ws_size, hipStream_t stream) {
  const float* x            = (const float*)d_in[0];
  const int*   cancer_type  = (const int*)d_in[1];
  const int*   channel_act  = (const int*)d_in[2];
  const float* Wq = (const float*)d_in[3];  const float* bq = (const float*)d_in[4];
  const float* Wk = (const float*)d_in[5];  const float* bk = (const float*)d_in[6];
  const float* Wv = (const float*)d_in[7];  const float* bv = (const float*)d_in[8];
  const float* Wo = (const float*)d_in[9];  const float* bo = (const float*)d_in[10];
  const float* ct_bias_emb = (const float*)d_in[11];
  const float* ct_key_emb  = (const float*)d_in[12];
  const float* ln1_g = (const float*)d_in[13]; const float* ln1_b = (const float*)d_in[14];
  const float* ln2_g = (const float*)d_in[15]; const float* ln2_b = (const float*)d_in[16];
  const float* W1 = (const float*)d_in[17]; const float* b1 = (const float*)d_in[18];
  const float* W2 = (const float*)d_in[19]; const float* b2 = (const float*)d_in[20];
  float* out = (float*)d_out;

  // workspace layout
  u16* WqkvT = (u16*)d_ws;                      // 3072 x 1024
  u16* WoT = WqkvT + (size_t)QKVN * 1024;       // 1024 x 1024
  u16* W1T = WoT + (size_t)1024 * 1024;         // 2048 x 1024
  u16* W2T = W1T + (size_t)2048 * 1024;         // 1024 x 2048
  u16* normed = W2T + (size_t)1024 * 2048;      // 65536 x 1024
  u16* QKV = normed + (size_t)MROWS * HIDN;     // 65536 x 3072
  u16* attnO = normed;                // reuse (normed dead after QKV gemm)
  u16* h2    = QKV;                   // reuse (QKV dead after attention)
  u16* act   = QKV + (size_t)MROWS * HIDN;  // 65536 x 2048 in QKV region
  float* x2  = (float*)d_out;         // residual stream lives in d_out

  const dim3 tb(32, 8);
  transpose_cast<<<dim3(32, 32), tb, 0, stream>>>(Wq, WqkvT, 1024, 1024);
  transpose_cast<<<dim3(32, 32), tb, 0, stream>>>(Wk, WqkvT + (size_t)1024 * 1024, 1024, 1024);
  transpose_cast<<<dim3(32, 32), tb, 0, stream>>>(Wv, WqkvT + (size_t)2048 * 1024, 1024, 1024);
  transpose_cast<<<dim3(32, 32), tb, 0, stream>>>(Wo, WoT, 1024, 1024);
  transpose_cast<<<dim3(64, 32), tb, 0, stream>>>(W1, W1T, 1024, 2048);
  transpose_cast<<<dim3(32, 64), tb, 0, stream>>>(W2, W2T, 2048, 1024);

  ln_kernel<<<MROWS, 256, 0, stream>>>(x, ln1_g, ln1_b, normed);

  // fused QKV: C = normed @ [Wq|Wk|Wv]  (65536 x 3072)
  gemm256<1><<<dim3(12, 256), 512, 0, stream>>>(
      normed, WqkvT, 1024, bq, bk, bv, nullptr, cancer_type, ct_key_emb,
      nullptr, QKV, QKVN);

  attn_kernel<<<BB, 256, 0, stream>>>(QKV, cancer_type, channel_act,
                                      ct_bias_emb, attnO);

  gemm256<2><<<dim3(4, 256), 512, 0, stream>>>(
      attnO, WoT, 1024, bo, nullptr, nullptr, x, nullptr, nullptr,
      x2, nullptr, 1024);

  ln_kernel<<<MROWS, 256, 0, stream>>>(x2, ln2_g, ln2_b, h2);

  gemm256<3><<<dim3(8, 256), 512, 0, stream>>>(
      h2, W1T, 1024, b1, nullptr, nullptr, nullptr, nullptr, nullptr,
      nullptr, act, 2048);

  gemm256<2><<<dim3(4, 256), 512, 0, stream>>>(
      act, W2T, 2048, b2, nullptr, nullptr, x2, nullptr, nullptr,
      out, nullptr, 1024);
}

// Round 3
// 2090.521 us; speedup vs baseline: 1.1589x; 1.0040x over previous
//
#include <hip/hip_runtime.h>
#include <hip/hip_bf16.h>

// Problem constants
#define BB   4096
#define CC   16
#define HIDN 1024
#define NHD  16
#define HDIM 64
#define MROWS (BB*CC)   // 65536
#define QKVN 3072

using u16 = unsigned short;
typedef __bf16 bf16x8 __attribute__((ext_vector_type(8)));
typedef float  f32x4  __attribute__((ext_vector_type(4)));
typedef int    v4i    __attribute__((ext_vector_type(4)));

__device__ __forceinline__ u16 f2b(float f) {
  union { __hip_bfloat16 h; u16 u; } c;
  c.h = __float2bfloat16(f);
  return c.u;
}

// ---------------------------------------------------------------------------
// Weight transpose + cast fp32 (R x C) -> bf16 (C x R)
// ---------------------------------------------------------------------------
__global__ __launch_bounds__(256) void transpose_cast(
    const float* __restrict__ src, u16* __restrict__ dst, int R, int C) {
  __shared__ float tile[32][33];
  const int bx = blockIdx.x * 32;  // col base in src
  const int by = blockIdx.y * 32;  // row base in src
  const int tx = threadIdx.x, ty = threadIdx.y;
#pragma unroll
  for (int jj = 0; jj < 32; jj += 8)
    tile[ty + jj][tx] = src[(long long)(by + ty + jj) * C + bx + tx];
  __syncthreads();
#pragma unroll
  for (int jj = 0; jj < 32; jj += 8)
    dst[(long long)(bx + ty + jj) * R + by + tx] = f2b(tile[tx][ty + jj]);
}

// ---------------------------------------------------------------------------
// Row LayerNorm fp32 -> bf16.  One block (256 thr) per row of 1024.
// ---------------------------------------------------------------------------
__global__ __launch_bounds__(256) void ln_kernel(
    const float* __restrict__ x, const float* __restrict__ g,
    const float* __restrict__ b, u16* __restrict__ out) {
  const int row = blockIdx.x;
  const int t = threadIdx.x;
  const float4 v = ((const float4*)(x + (long long)row * HIDN))[t];
  float s  = v.x + v.y + v.z + v.w;
  float sq = v.x * v.x + v.y * v.y + v.z * v.z + v.w * v.w;
#pragma unroll
  for (int off = 32; off; off >>= 1) {
    s  += __shfl_down(s, off);
    sq += __shfl_down(sq, off);
  }
  __shared__ float ws[8];
  const int w = t >> 6, lane = t & 63;
  if (lane == 0) { ws[w] = s; ws[4 + w] = sq; }
  __syncthreads();
  const float S  = ws[0] + ws[1] + ws[2] + ws[3];
  const float SQ = ws[4] + ws[5] + ws[6] + ws[7];
  const float mean = S * (1.f / HIDN);
  const float var  = SQ * (1.f / HIDN) - mean * mean;
  const float rstd = rsqrtf(var + 1e-5f);
  const float4 gg = ((const float4*)g)[t];
  const float4 bb = ((const float4*)b)[t];
  ushort4 o;
  o.x = f2b((v.x - mean) * rstd * gg.x + bb.x);
  o.y = f2b((v.y - mean) * rstd * gg.y + bb.y);
  o.z = f2b((v.z - mean) * rstd * gg.z + bb.z);
  o.w = f2b((v.w - mean) * rstd * gg.w + bb.w);
  ((ushort4*)(out + (long long)row * HIDN))[t] = o;
}

// ---------------------------------------------------------------------------
// GEMM: C[M,N] = A[M,K] @ B[K,N], A bf16 row-major, BT = B^T bf16 (N x K).
// 256x256 tile, BK=64, 512 threads = 8 waves (2M x 4N), 128 KiB LDS dbuf.
// 4 phases / K-tile: { asm ds_read subtile ; 1-2 half-tile global_load_lds ;
//   sched_barrier ; counted s_waitcnt vmcnt(N) (never 0 in main loop) ;
//   s_barrier ; s_waitcnt lgkmcnt(0)+sched_barrier ; setprio+16 MFMA ;
//   s_barrier }.
// LDS reads are inline-asm ds_read_b128 (compiler-INVISIBLE) so the memory
// legalizer does not insert vmcnt(0) drains before them.  vmcnt is PER-WAVE
// while half-tiles are staged by ALL waves, so every counted WAITV must be
// followed by s_barrier BEFORE any wave reads the landed half-tile (this
// round's fix: the drain tile was missing those barriers -> race).
// Wait accounting (steady state, 2 loads per STAGE):
//   entry of ph1: 4 in flight (Bh1,Ah1 of tile t)
//   ph1 issues Ah0,Bh0(t+1) -> 8 out, wait(6)+BAR lands Bh1(t)  [read ph2]
//   ph2 issues Bh1(t+1)     -> 8 out, wait(6)+BAR lands Ah1(t)  [read ph3]
//   ph3 issues Ah1(t+1)     -> 8 out, no wait
//   ph4 issues nothing      -> wait(4)+BAR lands Ah0,Bh0(t+1)   [next ph1]
// LDS chunk swizzle kc ^ (row&7) applied on the global source side
// (global_load_lds dest linear); read side folds it into per-thread bases
// since row&7 == l15&7 for every fragment row.
// EPI: 1 = fused QKV (per-block bias select + ct_key on K cols) -> bf16
//      2 = bias + fp32 residual -> fp32 ; 3 = bias + ELU -> bf16
// ---------------------------------------------------------------------------
#define TBM 256
#define TBN 256
#define TBK 64

template <int EPI>
__global__ __launch_bounds__(512, 2) void gemm256(
    const u16* __restrict__ A, const u16* __restrict__ BT, int K,
    const float* __restrict__ bias, const float* __restrict__ bias2,
    const float* __restrict__ bias3, const float* __restrict__ resid,
    const int* __restrict__ ctype, const float* __restrict__ ct_key,
    float* __restrict__ outF, u16* __restrict__ outB, int N) {
  // [buf][A=0/B=1][256 rows x 8 chunks x 8 u16]  = 128 KiB
  __shared__ __align__(16) u16 smem[2][2][TBM * TBK];

  const int t = threadIdx.x;
  const int lane = t & 63;
  const int w = t >> 6;
  const int l15 = lane & 15;
  const int quad = lane >> 4;
  const int wrow = w >> 2;  // 0..1 : 64-row group inside each 128-row half
  const int wcol = w & 3;   // 0..3 : 32-col group inside each 128-col half

  // bijective XCD swizzle (nwg % 8 == 0 for all launches here)
  const int gx = gridDim.x;
  const int nwg = gx * (int)gridDim.y;
  const int flat = (int)blockIdx.y * gx + (int)blockIdx.x;
  const int logical = (flat & 7) * (nwg >> 3) + (flat >> 3);
  const int nblk = logical % gx;  // N fast within an XCD chunk
  const int mblk = logical / gx;

  const long long Abase = (long long)mblk * TBM * K;
  const long long Bbase = (long long)nblk * TBN * K;

  // Stage one half-tile (128 rows x 64 k) of matrix `mat` into buf.
  // Linear LDS dest (wave base + lane*16); swizzle applied on global source.
  #define STAGE(buf, mat, h, kk, base, gp)                                       \
  do {                                                                           \
    _Pragma("unroll") for (int s_ = 0; s_ < 2; ++s_) {                           \
      const int idx_ = (h) * 1024 + (w * 2 + s_) * 64 + lane;                    \
      const int row_ = idx_ >> 3;                                                \
      const int kc_ = (idx_ & 7) ^ (row_ & 7);                                   \
      const u16* g_ = (gp) + (base) + (long long)row_ * K + (kk) + kc_ * 8;      \
      __builtin_amdgcn_global_load_lds(                                          \
          (const __attribute__((address_space(1))) void*)g_,                     \
          (__attribute__((address_space(3))) void*)(&smem[buf][mat][idx_ * 8]),  \
          16, 0, 0);                                                             \
    }                                                                            \
  } while (0)

  // ---- per-thread LDS read bases (byte addresses, swizzle pre-folded) ----
  const unsigned smA =
      (unsigned)(unsigned long long)(__attribute__((address_space(3))) void*)
          &smem[0][0][0];
  const unsigned smB = smA + 32768u;
  const unsigned swz0 = (unsigned)((quad ^ (l15 & 7)) * 16);        // ks=0
  const unsigned swz1 = (unsigned)(((4 + quad) ^ (l15 & 7)) * 16);  // ks=1
  const unsigned rowA0 = (unsigned)((wrow * 64 + l15) * 128);        // i=0
  const unsigned rowA1 = rowA0 + 128u * 128u;                        // i=1
  const unsigned rowB0 = (unsigned)((wcol * 32 + l15) * 128);        // j=0
  const unsigned rowB1 = rowB0 + 128u * 128u;                        // j=1

  v4i aR[4][2];   // 4 m-frags x 2 k-steps
  v4i bR[2][2];   // 2 n-frags x 2 k-steps

  #define DSR(d, b, IMM)                                                         \
    asm volatile("ds_read_b128 %0, %1 offset:" #IMM : "=&v"(d) : "v"(b))

  #define RDA(cboff, ri)                                                         \
  do {                                                                           \
    const unsigned bA0_ = smA + (cboff) + (ri) + swz0;                           \
    const unsigned bA1_ = smA + (cboff) + (ri) + swz1;                           \
    DSR(aR[0][0], bA0_, 0);    DSR(aR[0][1], bA1_, 0);                           \
    DSR(aR[1][0], bA0_, 2048); DSR(aR[1][1], bA1_, 2048);                        \
    DSR(aR[2][0], bA0_, 4096); DSR(aR[2][1], bA1_, 4096);                        \
    DSR(aR[3][0], bA0_, 6144); DSR(aR[3][1], bA1_, 6144);                        \
  } while (0)

  #define RDB(cboff, rj)                                                         \
  do {                                                                           \
    const unsigned bB0_ = smB + (cboff) + (rj) + swz0;                           \
    const unsigned bB1_ = smB + (cboff) + (rj) + swz1;                           \
    DSR(bR[0][0], bB0_, 0);    DSR(bR[0][1], bB1_, 0);                           \
    DSR(bR[1][0], bB0_, 2048); DSR(bR[1][1], bB1_, 2048);                        \
  } while (0)

  f32x4 acc[2][2][4][2] = {};  // [i row-half][j col-half][fm][fn]

  #define MM(i, j)                                                               \
  do {                                                                           \
    __builtin_amdgcn_s_setprio(1);                                               \
    _Pragma("unroll") for (int fm_ = 0; fm_ < 4; ++fm_)                          \
      _Pragma("unroll") for (int fn_ = 0; fn_ < 2; ++fn_)                        \
        _Pragma("unroll") for (int ks_ = 0; ks_ < 2; ++ks_)                      \
          acc[i][j][fm_][fn_] = __builtin_amdgcn_mfma_f32_16x16x32_bf16(         \
              __builtin_bit_cast(bf16x8, aR[fm_][ks_]),                          \
              __builtin_bit_cast(bf16x8, bR[fn_][ks_]),                          \
              acc[i][j][fm_][fn_], 0, 0, 0);                                     \
    __builtin_amdgcn_s_setprio(0);                                               \
  } while (0)

  #define WAITV(n) asm volatile("s_waitcnt vmcnt(" #n ")")
  #define LGKM0()  asm volatile("s_waitcnt lgkmcnt(0)")
  #define SB0()    __builtin_amdgcn_sched_barrier(0)
  #define BAR()    __builtin_amdgcn_s_barrier()

  // ---- prologue: tile 0, issue order [Ah0, Bh0, Bh1, Ah1] (8 loads)
  STAGE(0, 0, 0, 0, Abase, A);
  STAGE(0, 1, 0, 0, Bbase, BT);
  STAGE(0, 1, 1, 0, Bbase, BT);
  STAGE(0, 0, 1, 0, Abase, A);
  SB0(); WAITV(4);   // Ah0(0), Bh0(0) resident; Bh1(0), Ah1(0) in flight
  BAR();

  const int NT = K >> 6;
  for (int tt = 0; tt < NT - 1; ++tt) {
    const unsigned cboff = (unsigned)(tt & 1) << 16;  // current buf byte off
    const int nb = (tt & 1) ^ 1;
    const int kk = (tt + 1) << 6;
    // ph1: C(0,0).  Issue Ah0,Bh0(t+1).  wait(6)+BAR lands Bh1(t) for ph2.
    RDA(cboff, rowA0); RDB(cboff, rowB0);
    STAGE(nb, 0, 0, kk, Abase, A);
    STAGE(nb, 1, 0, kk, Bbase, BT);
    SB0(); WAITV(6); BAR();
    LGKM0(); SB0();
    MM(0, 0);
    SB0(); BAR();
    // ph2: C(0,1).  Issue Bh1(t+1).  wait(6)+BAR lands Ah1(t) for ph3.
    RDB(cboff, rowB1);
    STAGE(nb, 1, 1, kk, Bbase, BT);
    SB0(); WAITV(6); BAR();
    LGKM0(); SB0();
    MM(0, 1);
    SB0(); BAR();
    // ph3: C(1,1).  Issue Ah1(t+1).  Nothing new needed by ph4.
    RDA(cboff, rowA1);
    STAGE(nb, 0, 1, kk, Abase, A);
    SB0(); BAR();
    LGKM0(); SB0();
    MM(1, 1);
    SB0(); BAR();
    // ph4: C(1,0).  wait(4)+BAR lands Ah0,Bh0(t+1) for next ph1.
    RDB(cboff, rowB0);
    SB0(); WAITV(4); BAR();
    LGKM0(); SB0();
    MM(1, 0);
    SB0(); BAR();
  }
  // ---- last tile (no prefetch).  Every counted wait is followed by BAR
  // before any dependent LDS read: vmcnt is per-wave but half-tiles are
  // staged by all 8 waves (round-2 bug was missing these barriers).
  {
    const unsigned cboff = (unsigned)((NT - 1) & 1) << 16;
    RDA(cboff, rowA0); RDB(cboff, rowB0);   // landed via loop ph4 wait(4)+BAR
    LGKM0(); SB0();
    MM(0, 0);
    SB0(); WAITV(2); BAR();                 // all waves' Bh1 loads landed
    RDB(cboff, rowB1);
    LGKM0(); SB0();
    MM(0, 1);
    SB0(); WAITV(0); BAR();                 // all waves' Ah1 loads landed
    RDA(cboff, rowA1);
    LGKM0(); SB0();
    MM(1, 1);
    RDB(cboff, rowB0);
    LGKM0(); SB0();
    MM(1, 0);
  }

  #undef STAGE
  #undef DSR
  #undef RDA
  #undef RDB
  #undef MM
  #undef WAITV
  #undef LGKM0
  #undef SB0
  #undef BAR

  // ---- epilogue.  C/D layout: col = lane&15, row = quad*4 + r  (unchanged)
  const float* bsel = bias;
  bool addct = false;
  if constexpr (EPI == 1) {
    const int sub = nblk >> 2;  // 256-col block fully inside one 1024 slice
    bsel = (sub == 0) ? bias : (sub == 1 ? bias2 : bias3);
    addct = (sub == 1);
  }

#pragma unroll
  for (int i = 0; i < 2; ++i) {
#pragma unroll
    for (int j = 0; j < 2; ++j) {
#pragma unroll
      for (int fn = 0; fn < 2; ++fn) {
        const int col = nblk * TBN + j * 128 + wcol * 32 + fn * 16 + l15;
        float bv;
        if constexpr (EPI == 1) {
          bv = bsel[col & 1023];
        } else {
          bv = bias[col];
        }
#pragma unroll
        for (int fm = 0; fm < 4; ++fm) {
#pragma unroll
          for (int r = 0; r < 4; ++r) {
            const int row =
                mblk * TBM + i * 128 + wrow * 64 + fm * 16 + quad * 4 + r;
            float v = acc[i][j][fm][fn][r] + bv;
            const long long oidx = (long long)row * N + col;
            if constexpr (EPI == 1) {
              if (addct)
                v += ct_key[(long long)ctype[row >> 4] * HIDN + (col & 1023)];
              outB[oidx] = f2b(v);
            } else if constexpr (EPI == 2) {
              outF[oidx] = v + resid[oidx];
            } else if constexpr (EPI == 3) {
              v = v > 0.f ? v : __expf(v) - 1.f;
              outB[oidx] = f2b(v);
            } else {
              outB[oidx] = f2b(v);
            }
          }
        }
      }
    }
  }
}

// ---------------------------------------------------------------------------
// Per-batch attention. 1 block / batch, thread = (head h, query i).
// QKV bf16 interleaved (MROWS x 3072): [Q(1024) | K(1024) | V(1024)] per row.
// out bf16 (MROWS x 1024).
// ---------------------------------------------------------------------------
__global__ __launch_bounds__(256) void attn_kernel(
    const u16* __restrict__ QKV, const int* __restrict__ cancer_type,
    const int* __restrict__ channel_active,
    const float* __restrict__ ct_bias_emb, u16* __restrict__ out) {
  __shared__ u16 Ks[CC * HIDN];  // 32 KB
  __shared__ u16 Vs[CC * HIDN];  // 32 KB
  const int b = blockIdx.x;
  const int t = threadIdx.x;

#pragma unroll
  for (int j = 0; j < 8; ++j) {
    const int c = j * 256 + t;     // c = row*128 + off
    const int row = c >> 7;
    const int off = c & 127;
    const long long base = (long long)(b * CC + row) * QKVN;
    ((float4*)Ks)[c] = *(const float4*)(QKV + base + 1024 + off * 8);
    ((float4*)Vs)[c] = *(const float4*)(QKV + base + 2048 + off * 8);
  }
  __syncthreads();

  const int h = t >> 4, i = t & 15;
  const int ct = cancer_type[b];
  const float* ctb = ct_bias_emb + ct * (CC * CC) + i * CC;

  // load q row (64 floats)
  float q[HDIM];
  const u16* qg = QKV + ((long long)(b * CC + i) * QKVN + h * HDIM);
#pragma unroll
  for (int c = 0; c < 8; ++c) {
    const bf16x8 v = *(const bf16x8*)(qg + c * 8);
#pragma unroll
    for (int e = 0; e < 8; ++e) q[c * 8 + e] = (float)v[e];
  }

  // scores
  float s[CC];
#pragma unroll
  for (int j = 0; j < CC; ++j) {
    const u16* kr = Ks + j * HIDN + h * HDIM;
    float a = 0.f;
#pragma unroll
    for (int c = 0; c < 8; ++c) {
      const bf16x8 kv = *(const bf16x8*)(kr + c * 8);
#pragma unroll
      for (int e = 0; e < 8; ++e) a += q[c * 8 + e] * (float)kv[e];
    }
    a = a * 0.125f + 0.1f * ctb[j];
    if (channel_active[b * CC + j] == 0) a = -__builtin_inff();
    s[j] = a;
  }

  // softmax with all-masked -> zeros (nan_to_num)
  float mx = -__builtin_inff();
#pragma unroll
  for (int j = 0; j < CC; ++j) mx = fmaxf(mx, s[j]);
  float p[CC];
  float sum = 0.f;
  const bool dead = (mx == -__builtin_inff());
#pragma unroll
  for (int j = 0; j < CC; ++j) {
    p[j] = dead ? 0.f : __expf(s[j] - mx);
    sum += p[j];
  }
  const float inv = sum > 0.f ? 1.f / sum : 0.f;

  // P @ V
  float o[HDIM] = {};
#pragma unroll
  for (int j = 0; j < CC; ++j) {
    const float pw = p[j] * inv;
    const u16* vr = Vs + j * HIDN + h * HDIM;
#pragma unroll
    for (int c = 0; c < 8; ++c) {
      const bf16x8 vv = *(const bf16x8*)(vr + c * 8);
#pragma unroll
      for (int e = 0; e < 8; ++e) o[c * 8 + e] += pw * (float)vv[e];
    }
  }

  u16* og = out + ((long long)(b * CC + i) * HIDN + h * HDIM);
#pragma unroll
  for (int c = 0; c < 8; ++c) {
    uint4 u;
    u.x = (unsigned)f2b(o[c * 8 + 0]) | ((unsigned)f2b(o[c * 8 + 1]) << 16);
    u.y = (unsigned)f2b(o[c * 8 + 2]) | ((unsigned)f2b(o[c * 8 + 3]) << 16);
    u.z = (unsigned)f2b(o[c * 8 + 4]) | ((unsigned)f2b(o[c * 8 + 5]) << 16);
    u.w = (unsigned)f2b(o[c * 8 + 6]) | ((unsigned)f2b(o[c * 8 + 7]) << 16);
    ((uint4*)og)[c] = u;
  }
}

// ---------------------------------------------------------------------------
extern "C" void kernel_launch(void* const* d_in, const int* in_sizes, int n_in,
                              void* d_out, int out_size, void* d_ws,
                              size_t ws_size, hipStream_t stream) {
  const float* x            = (const float*)d_in[0];
  const int*   cancer_type  = (const int*)d_in[1];
  const int*   channel_act  = (const int*)d_in[2];
  const float* Wq = (const float*)d_in[3];  const float* bq = (const float*)d_in[4];
  const float* Wk = (const float*)d_in[5];  const float* bk = (const float*)d_in[6];
  const float* Wv = (const float*)d_in[7];  const float* bv = (const float*)d_in[8];
  const float* Wo = (const float*)d_in[9];  const float* bo = (const float*)d_in[10];
  const float* ct_bias_emb = (const float*)d_in[11];
  const float* ct_key_emb  = (const float*)d_in[12];
  const float* ln1_g = (const float*)d_in[13]; const float* ln1_b = (const float*)d_in[14];
  const float* ln2_g = (const float*)d_in[15]; const float* ln2_b = (const float*)d_in[16];
  const float* W1 = (const float*)d_in[17]; const float* b1 = (const float*)d_in[18];
  const float* W2 = (const float*)d_in[19]; const float* b2 = (const float*)d_in[20];
  float* out = (float*)d_out;

  // workspace layout
  u16* WqkvT = (u16*)d_ws;                      // 3072 x 1024
  u16* WoT = WqkvT + (size_t)QKVN * 1024;       // 1024 x 1024
  u16* W1T = WoT + (size_t)1024 * 1024;         // 2048 x 1024
  u16* W2T = W1T + (size_t)2048 * 1024;         // 1024 x 2048
  u16* normed = W2T + (size_t)1024 * 2048;      // 65536 x 1024
  u16* QKV = normed + (size_t)MROWS * HIDN;     // 65536 x 3072
  u16* attnO = normed;                // reuse (normed dead after QKV gemm)
  u16* h2    = QKV;                   // reuse (QKV dead after attention)
  u16* act   = QKV + (size_t)MROWS * HIDN;  // 65536 x 2048 in QKV region
  float* x2  = (float*)d_out;         // residual stream lives in d_out

  const dim3 tb(32, 8);
  transpose_cast<<<dim3(32, 32), tb, 0, stream>>>(Wq, WqkvT, 1024, 1024);
  transpose_cast<<<dim3(32, 32), tb, 0, stream>>>(Wk, WqkvT + (size_t)1024 * 1024, 1024, 1024);
  transpose_cast<<<dim3(32, 32), tb, 0, stream>>>(Wv, WqkvT + (size_t)2048 * 1024, 1024, 1024);
  transpose_cast<<<dim3(32, 32), tb, 0, stream>>>(Wo, WoT, 1024, 1024);
  transpose_cast<<<dim3(64, 32), tb, 0, stream>>>(W1, W1T, 1024, 2048);
  transpose_cast<<<dim3(32, 64), tb, 0, stream>>>(W2, W2T, 2048, 1024);

  ln_kernel<<<MROWS, 256, 0, stream>>>(x, ln1_g, ln1_b, normed);

  // fused QKV: C = normed @ [Wq|Wk|Wv]  (65536 x 3072)
  gemm256<1><<<dim3(12, 256), 512, 0, stream>>>(
      normed, WqkvT, 1024, bq, bk, bv, nullptr, cancer_type, ct_key_emb,
      nullptr, QKV, QKVN);

  attn_kernel<<<BB, 256, 0, stream>>>(QKV, cancer_type, channel_act,
                                      ct_bias_emb, attnO);

  gemm256<2><<<dim3(4, 256), 512, 0, stream>>>(
      attnO, WoT, 1024, bo, nullptr, nullptr, x, nullptr, nullptr,
      x2, nullptr, 1024);

  ln_kernel<<<MROWS, 256, 0, stream>>>(x2, ln2_g, ln2_b, h2);

  gemm256<3><<<dim3(8, 256), 512, 0, stream>>>(
      h2, W1T, 1024, b1, nullptr, nullptr, nullptr, nullptr, nullptr,
      nullptr, act, 2048);

  gemm256<2><<<dim3(4, 256), 512, 0, stream>>>(
      act, W2T, 2048, b2, nullptr, nullptr, x2, nullptr, nullptr,
      out, nullptr, 1024);
}